// Round 1
// baseline (1530.537 us; speedup 1.0000x reference)
//
#include <hip/hip_runtime.h>
#include <stdint.h>

#define CDIM   256
#define NPIX   65536
#define NBATCH 8
#define WCOLS  64
#define NTILES (NPIX / WCOLS)   // 1024
#define KTHRESH 0.01

// workspace layout (float indices)
#define WS_DELTA 0        // 256 floats: normalize(c1)-normalize(c0)
#define WS_CENT  256      // 512 floats: current raw centers [K][C]
#define WS_T     768      // 2048 floats: per-batch totals  T[b][c]
#define WS_S1    2816     // 2048 floats: per-batch label-1 sums S1[b][c]
#define WS_CNT   4864     // 8 uints: per-batch label-1 counts
#define WS_DONE  4872     // 1 int: convergence flag

// output layout (floats): centers[2*256] | labels[8*65536] | onehot[8*65536*2] | cur_dist
#define OUT_LABELS 512
#define OUT_ONEHOT (512 + NBATCH * NPIX)
#define OUT_CDIST  (512 + NBATCH * NPIX + 2 * NBATCH * NPIX)

__device__ __forceinline__ double block_reduce(double v, double* sh) {
  const int t = threadIdx.x;
  #pragma unroll
  for (int off = 32; off > 0; off >>= 1) v += __shfl_down(v, off, 64);
  __syncthreads();              // protect sh reuse across sequential calls
  if ((t & 63) == 0) sh[t >> 6] = v;
  __syncthreads();
  return sh[0] + sh[1] + sh[2] + sh[3];
}

__global__ __launch_bounds__(256) void init_kernel(const float* __restrict__ cinit,
                                                   float* __restrict__ ws) {
  __shared__ double sh[4];
  const int t = threadIdx.x;
  for (int i = t; i < NBATCH * CDIM; i += 256) { ws[WS_T + i] = 0.f; ws[WS_S1 + i] = 0.f; }
  if (t < NBATCH) ((unsigned int*)(ws + WS_CNT))[t] = 0u;
  if (t == 0) ((int*)(ws + WS_DONE))[0] = 0;
  const float c0f = cinit[t], c1f = cinit[CDIM + t];
  ws[WS_CENT + t] = c0f;
  ws[WS_CENT + CDIM + t] = c1f;
  const double c0 = (double)c0f, c1 = (double)c1f;
  double n0 = sqrt(block_reduce(c0 * c0, sh));
  double n1 = sqrt(block_reduce(c1 * c1, sh));
  n0 = fmax(n0, 1e-12); n1 = fmax(n1, 1e-12);
  ws[WS_DELTA + t] = (float)(c1 / n1) - (float)(c0 / n0);
}

// One block = one (batch, 64-column) tile of the [C=256, N=65536] matrix.
// Stage tile to LDS; fp64 partial dots computed during staging; then labels,
// outputs, and masked per-channel sums from the LDS-resident tile.
__global__ __launch_bounds__(256) void pass_kernel(const float* __restrict__ F,
                                                   float* __restrict__ ws,
                                                   float* __restrict__ out,
                                                   int iter) {
  if (iter > 0 && ((const volatile int*)(ws + WS_DONE))[0] != 0) return;

  __shared__ float  tileS[CDIM * (WCOLS + 1)];   // stride 65: conflict-free phases
  __shared__ float  deltaS[CDIM];
  __shared__ double pd[16 * WCOLS];              // partial dots [rowgroup][col]
  __shared__ float  mS[WCOLS];                   // labels as float

  const int t    = threadIdx.x;
  const int b    = blockIdx.x >> 10;             // NTILES = 1024
  const int tile = blockIdx.x & (NTILES - 1);
  const int n0   = tile * WCOLS;

  deltaS[t] = ws[WS_DELTA + t];
  __syncthreads();

  const int inner = t & 15;                      // 16 x float4 = 64 columns
  const int rgrp  = t >> 4;                      // 16 row-groups
  const float* Fb = F + ((size_t)b * CDIM) * (size_t)NPIX + (size_t)n0 + (size_t)inner * 4;
  double p0 = 0.0, p1 = 0.0, p2 = 0.0, p3 = 0.0;
  #pragma unroll
  for (int it = 0; it < 16; ++it) {
    const int c = it * 16 + rgrp;
    const float4 v = *(const float4*)(Fb + (size_t)c * NPIX);
    const double dc = (double)deltaS[c];
    p0 = fma(dc, (double)v.x, p0);
    p1 = fma(dc, (double)v.y, p1);
    p2 = fma(dc, (double)v.z, p2);
    p3 = fma(dc, (double)v.w, p3);
    float* dst = &tileS[c * (WCOLS + 1) + inner * 4];
    dst[0] = v.x; dst[1] = v.y; dst[2] = v.z; dst[3] = v.w;
  }
  double* pdst = &pd[rgrp * WCOLS + inner * 4];
  pdst[0] = p0; pdst[1] = p1; pdst[2] = p2; pdst[3] = p3;
  __syncthreads();

  if (t < WCOLS) {
    double d = 0.0;
    #pragma unroll
    for (int r = 0; r < 16; ++r) d += pd[r * WCOLS + t];
    const float m = d > 0.0 ? 1.0f : 0.0f;       // label: argmax_k f.cn_k ; tie -> 0
    mS[t] = m;
    const int gi = b * NPIX + n0 + t;
    out[OUT_LABELS + gi] = m;
    ((float2*)(out + OUT_ONEHOT))[gi] = make_float2(1.0f - m, m);
    const unsigned long long ba = __ballot(d > 0.0);
    if (t == 0)
      atomicAdd(&((unsigned int*)(ws + WS_CNT))[b], (unsigned int)__popcll(ba));
  }
  __syncthreads();

  // phase 2: thread t owns channel c = t; masked sum over the 64 tile columns
  float s1 = 0.f, tot = 0.f;
  const float* row = &tileS[t * (WCOLS + 1)];
  #pragma unroll
  for (int n = 0; n < WCOLS; ++n) {
    const float v = row[n];
    s1 = fmaf(mS[n], v, s1);
    tot += v;
  }
  unsafeAtomicAdd(&ws[WS_S1 + b * CDIM + t], s1);
  if (iter == 0) unsafeAtomicAdd(&ws[WS_T + b * CDIM + t], tot);  // T is iteration-invariant
}

__global__ __launch_bounds__(256) void finalize_kernel(float* __restrict__ ws,
                                                       float* __restrict__ out) {
  __shared__ double sh[4];
  const int t = threadIdx.x;
  if (((const volatile int*)(ws + WS_DONE))[0] != 0) return;  // frozen: keep prior outputs

  const double cold0 = (double)ws[WS_CENT + t];
  const double cold1 = (double)ws[WS_CENT + CDIM + t];
  const double normc0 = sqrt(block_reduce(cold0 * cold0, sh));
  const double normc1 = sqrt(block_reduce(cold1 * cold1, sh));

  double acc0 = 0.0, acc1 = 0.0, cdsum = 0.0;
  for (int b = 0; b < NBATCH; ++b) {
    const double s1v  = (double)ws[WS_S1 + b * CDIM + t];
    const double totv = (double)ws[WS_T  + b * CDIM + t];
    const double c1n  = (double)((unsigned int*)(ws + WS_CNT))[b];
    const double ci1  = s1v / (c1n + 1.0);
    const double ci0  = (totv - s1v) / ((double)NPIX - c1n + 1.0);
    acc0 += ci0; acc1 += ci1;
    const double num0 = block_reduce(ci0 * cold0, sh);
    const double q0   = block_reduce(ci0 * ci0,   sh);
    const double num1 = block_reduce(ci1 * cold1, sh);
    const double q1   = block_reduce(ci1 * ci1,   sh);
    const double den0 = fmax(sqrt(q0) * normc0, 1e-8);
    const double den1 = fmax(sqrt(q1) * normc1, 1e-8);
    cdsum += 0.5 * (num0 / den0 + num1 / den1);
  }
  const double curdist = cdsum / (double)NBATCH;
  const float nc0f = (float)(acc0 / (double)NBATCH);
  const float nc1f = (float)(acc1 / (double)NBATCH);

  ws[WS_CENT + t] = nc0f;
  ws[WS_CENT + CDIM + t] = nc1f;
  out[t] = nc0f;
  out[CDIM + t] = nc1f;
  if (t == 0) out[OUT_CDIST] = (float)curdist;

  // delta for the next pass, from fp32-rounded new centers (matches ref semantics)
  double m0 = sqrt(block_reduce((double)nc0f * (double)nc0f, sh));
  double m1 = sqrt(block_reduce((double)nc1f * (double)nc1f, sh));
  m0 = fmax(m0, 1e-12); m1 = fmax(m1, 1e-12);
  ws[WS_DELTA + t] = (float)((double)nc1f / m1) - (float)((double)nc0f / m0);

  __syncthreads();
  for (int i = t; i < NBATCH * CDIM; i += 256) ws[WS_S1 + i] = 0.f;
  if (t < NBATCH) ((unsigned int*)(ws + WS_CNT))[t] = 0u;
  if (t == 0) ((int*)(ws + WS_DONE))[0] = (curdist < KTHRESH) ? 1 : 0;
}

extern "C" void kernel_launch(void* const* d_in, const int* in_sizes, int n_in,
                              void* d_out, int out_size, void* d_ws, size_t ws_size,
                              hipStream_t stream) {
  const float* F     = (const float*)d_in[0];
  const float* cinit = (const float*)d_in[1];
  float* out = (float*)d_out;
  float* ws  = (float*)d_ws;

  init_kernel<<<1, 256, 0, stream>>>(cinit, ws);
  for (int iter = 0; iter < 3; ++iter) {
    pass_kernel<<<NBATCH * NTILES, 256, 0, stream>>>(F, ws, out, iter);
    finalize_kernel<<<1, 256, 0, stream>>>(ws, out);
  }
}

// Round 2
// 1135.174 us; speedup vs baseline: 1.3483x; 1.3483x over previous
//
#include <hip/hip_runtime.h>
#include <stdint.h>

#define CDIM   256
#define NPIX   65536
#define NBATCH 8
#define WCOLS  64
#define NTILES 1024                       // tiles per batch (NPIX/WCOLS)
#define TPB    16                         // tiles per block
#define NBLOCKS (NBATCH * NTILES / TPB)   // 512
#define KTHRESH 0.01

// workspace layout (float indices)
#define WS_DELTA 0        // 256 floats: normalize(c1)-normalize(c0)
#define WS_CENT  256      // 512 floats: current raw centers [K][C]
#define WS_T     768      // 2048 floats: per-batch totals  T[b][c]
#define WS_S1    2816     // 2048 floats: per-batch label-1 sums S1[b][c]
#define WS_CNT   4864     // 8 uints: per-batch label-1 counts
#define WS_DONE  4872     // 1 int: convergence flag

// output layout (floats): centers[2*256] | labels[8*65536] | onehot[8*65536*2] | cur_dist
#define OUT_LABELS 512
#define OUT_ONEHOT (512 + NBATCH * NPIX)
#define OUT_CDIST  (512 + NBATCH * NPIX + 2 * NBATCH * NPIX)

// tile LDS geometry: row c at word 65*c + 8*(c>>6); 64 data words per row.
// -> phase1 (column reads, 4 cseg x 16 cols) and phase2 (per-channel row reads)
//    both land 2 lanes/bank = conflict-free.  max word 65*255+24+63 = 16662.
#define TILE_WORDS 16664

__device__ __forceinline__ void dma_row4(const float* g, float* l) {
  // async global->LDS, 4 bytes per lane; LDS dst = wave-uniform base + lane*4
  __builtin_amdgcn_global_load_lds((const __attribute__((address_space(1))) void*)g,
                                   (__attribute__((address_space(3))) void*)l, 4, 0, 0);
}

__device__ __forceinline__ double block_reduce(double v, double* sh) {
  const int t = threadIdx.x;
  #pragma unroll
  for (int off = 32; off > 0; off >>= 1) v += __shfl_down(v, off, 64);
  __syncthreads();
  if ((t & 63) == 0) sh[t >> 6] = v;
  __syncthreads();
  return sh[0] + sh[1] + sh[2] + sh[3];
}

__device__ __forceinline__ void block_reduce4(double v[4], double* sh) {
  const int t = threadIdx.x;
  #pragma unroll
  for (int off = 32; off > 0; off >>= 1) {
    v[0] += __shfl_down(v[0], off, 64);
    v[1] += __shfl_down(v[1], off, 64);
    v[2] += __shfl_down(v[2], off, 64);
    v[3] += __shfl_down(v[3], off, 64);
  }
  __syncthreads();
  if ((t & 63) == 0) {
    const int w = t >> 6;
    sh[w] = v[0]; sh[4 + w] = v[1]; sh[8 + w] = v[2]; sh[12 + w] = v[3];
  }
  __syncthreads();
  #pragma unroll
  for (int k = 0; k < 4; ++k) v[k] = sh[4 * k] + sh[4 * k + 1] + sh[4 * k + 2] + sh[4 * k + 3];
}

__global__ __launch_bounds__(256) void init_kernel(const float* __restrict__ cinit,
                                                   float* __restrict__ ws) {
  __shared__ double sh[16];
  const int t = threadIdx.x;
  for (int i = t; i < NBATCH * CDIM; i += 256) { ws[WS_T + i] = 0.f; ws[WS_S1 + i] = 0.f; }
  if (t < NBATCH) ((unsigned int*)(ws + WS_CNT))[t] = 0u;
  if (t == 0) ((int*)(ws + WS_DONE))[0] = 0;
  const float c0f = cinit[t], c1f = cinit[CDIM + t];
  ws[WS_CENT + t] = c0f;
  ws[WS_CENT + CDIM + t] = c1f;
  const double c0 = (double)c0f, c1 = (double)c1f;
  double n0 = sqrt(block_reduce(c0 * c0, sh));
  double n1 = sqrt(block_reduce(c1 * c1, sh));
  n0 = fmax(n0, 1e-12); n1 = fmax(n1, 1e-12);
  ws[WS_DELTA + t] = (float)(c1 / n1) - (float)(c0 / n0);
}

// persistent double-buffered streaming pass: 512 blocks, 16 tiles each.
// per tile: [barrier: tile ready] -> issue DMA(tile+1) -> barrier-free compute.
__global__ __launch_bounds__(256, 1) void pass_kernel(const float* __restrict__ F,
                                                      float* __restrict__ ws,
                                                      float* __restrict__ out,
                                                      int iter) {
  if (iter > 0 && ((const volatile int*)(ws + WS_DONE))[0] != 0) return;

  __shared__ float tile[2][TILE_WORDS];          // 2 x 65.1 KB -> 1 block/CU
  __shared__ float deltaS[4 * 72];               // delta, seg-padded (bank-safe bcast)

  const int t  = threadIdx.x;
  const int w  = t >> 6;                         // wave 0..3
  const int l  = t & 63;                         // lane
  const int b  = blockIdx.x >> 6;                // 64 blocks per batch
  const int tile0 = (blockIdx.x & 63) * TPB;

  if (t < CDIM) deltaS[(t >> 6) * 72 + (t & 63)] = ws[WS_DELTA + t];

  const float* Fb = F + (size_t)b * CDIM * NPIX;

  // prologue: DMA tile0 -> buf 0 (wave w stages rows w*64 .. w*64+63)
  {
    const size_t g0 = (size_t)(tile0 * WCOLS) + l;
    #pragma unroll
    for (int r = 0; r < 64; ++r) {
      const int c = w * 64 + r;
      dma_row4(Fb + (size_t)c * NPIX + g0, &tile[0][65 * c + 8 * (c >> 6) + l]);
    }
  }

  float s1[4] = {0.f, 0.f, 0.f, 0.f};
  float tv[4] = {0.f, 0.f, 0.f, 0.f};
  unsigned cnt = 0;

  const int cseg = l >> 4;                       // phase1: channel segment 0..3
  const int q    = l & 15;                       //         column within wave's 16
  const int nloc = w * 16 + q;                   //         column within tile

  int buf = 0;
  for (int i = 0; i < TPB; ++i) {
    asm volatile("s_waitcnt vmcnt(0)" ::: "memory");
    __syncthreads();                             // tile i landed (all waves drained)

    if (i + 1 < TPB) {                           // DMA next tile during compute
      const size_t g0 = (size_t)((tile0 + i + 1) * WCOLS) + l;
      float* dst = tile[buf ^ 1];
      #pragma unroll
      for (int r = 0; r < 64; ++r) {
        const int c = w * 64 + r;
        dma_row4(Fb + (size_t)c * NPIX + g0, &dst[65 * c + 8 * (c >> 6) + l]);
      }
    }

    const float* T = tile[buf];

    // phase 1: fp64 partial dot for column nloc over channels [cseg*64, +64)
    double d = 0.0;
    const float* Tcol = T + (size_t)(cseg * 64) * 65 + 8 * cseg + nloc;
    const float* dl = deltaS + cseg * 72;
    #pragma unroll
    for (int j = 0; j < 64; ++j)
      d = fma((double)dl[j], (double)Tcol[(size_t)j * 65], d);
    d += __shfl_down(d, 32, 64);
    d += __shfl_down(d, 16, 64);                 // lanes 0..15 hold full dots
    const unsigned long long ball = __ballot(d > 0.0);
    const unsigned mask16 = (unsigned)(ball & 0xFFFFull);  // wave-uniform labels
    cnt += __popc(mask16);

    const int n0 = (tile0 + i) * WCOLS;
    if (l < 16) {
      const float m = (float)((mask16 >> l) & 1u);
      const int gi = b * NPIX + n0 + w * 16 + l;
      out[OUT_LABELS + gi] = m;
      ((float2*)(out + OUT_ONEHOT))[gi] = make_float2(1.0f - m, m);
    }

    // phase 2: lane owns channels l+64k over this wave's 16 columns
    #pragma unroll
    for (int k = 0; k < 4; ++k) {
      const float* row = T + (size_t)(l + 64 * k) * 65 + 8 * k + w * 16;
      float a1 = 0.f, at = 0.f;
      #pragma unroll
      for (int qq = 0; qq < 16; ++qq) {
        const float v = row[qq];
        a1 = fmaf((float)((mask16 >> qq) & 1u), v, a1);
        at += v;
      }
      s1[k] += a1;
      tv[k] += at;
    }
    buf ^= 1;
  }

  #pragma unroll
  for (int k = 0; k < 4; ++k) {
    unsafeAtomicAdd(&ws[WS_S1 + b * CDIM + l + 64 * k], s1[k]);
    if (iter == 0) unsafeAtomicAdd(&ws[WS_T + b * CDIM + l + 64 * k], tv[k]);
  }
  if (l == 0) atomicAdd(&((unsigned int*)(ws + WS_CNT))[b], cnt);
}

__global__ __launch_bounds__(256) void finalize_kernel(float* __restrict__ ws,
                                                       float* __restrict__ out) {
  __shared__ double sh[16];
  const int t = threadIdx.x;
  if (((const volatile int*)(ws + WS_DONE))[0] != 0) return;  // frozen: keep prior outputs

  const double cold0 = (double)ws[WS_CENT + t];
  const double cold1 = (double)ws[WS_CENT + CDIM + t];
  const double normc0 = sqrt(block_reduce(cold0 * cold0, sh));
  const double normc1 = sqrt(block_reduce(cold1 * cold1, sh));

  double acc0 = 0.0, acc1 = 0.0, cdsum = 0.0;
  for (int b = 0; b < NBATCH; ++b) {
    const double s1v  = (double)ws[WS_S1 + b * CDIM + t];
    const double totv = (double)ws[WS_T  + b * CDIM + t];
    const double c1n  = (double)((unsigned int*)(ws + WS_CNT))[b];
    const double ci1  = s1v / (c1n + 1.0);
    const double ci0  = (totv - s1v) / ((double)NPIX - c1n + 1.0);
    acc0 += ci0; acc1 += ci1;
    double v[4] = {ci0 * cold0, ci0 * ci0, ci1 * cold1, ci1 * ci1};
    block_reduce4(v, sh);
    const double den0 = fmax(sqrt(v[1]) * normc0, 1e-8);
    const double den1 = fmax(sqrt(v[3]) * normc1, 1e-8);
    cdsum += 0.5 * (v[0] / den0 + v[2] / den1);
  }
  const double curdist = cdsum / (double)NBATCH;
  const float nc0f = (float)(acc0 / (double)NBATCH);
  const float nc1f = (float)(acc1 / (double)NBATCH);

  ws[WS_CENT + t] = nc0f;
  ws[WS_CENT + CDIM + t] = nc1f;
  out[t] = nc0f;
  out[CDIM + t] = nc1f;
  if (t == 0) out[OUT_CDIST] = (float)curdist;

  double m0 = sqrt(block_reduce((double)nc0f * (double)nc0f, sh));
  double m1 = sqrt(block_reduce((double)nc1f * (double)nc1f, sh));
  m0 = fmax(m0, 1e-12); m1 = fmax(m1, 1e-12);
  ws[WS_DELTA + t] = (float)((double)nc1f / m1) - (float)((double)nc0f / m0);

  __syncthreads();
  for (int i = t; i < NBATCH * CDIM; i += 256) ws[WS_S1 + i] = 0.f;
  if (t < NBATCH) ((unsigned int*)(ws + WS_CNT))[t] = 0u;
  if (t == 0) ((int*)(ws + WS_DONE))[0] = (curdist < KTHRESH) ? 1 : 0;
}

extern "C" void kernel_launch(void* const* d_in, const int* in_sizes, int n_in,
                              void* d_out, int out_size, void* d_ws, size_t ws_size,
                              hipStream_t stream) {
  const float* F     = (const float*)d_in[0];
  const float* cinit = (const float*)d_in[1];
  float* out = (float*)d_out;
  float* ws  = (float*)d_ws;

  init_kernel<<<1, 256, 0, stream>>>(cinit, ws);
  for (int iter = 0; iter < 3; ++iter) {
    pass_kernel<<<NBLOCKS, 256, 0, stream>>>(F, ws, out, iter);
    finalize_kernel<<<1, 256, 0, stream>>>(ws, out);
  }
}